// Round 5
// baseline (798.867 us; speedup 1.0000x reference)
//
#include <hip/hip_runtime.h>
#include <hip/hip_fp16.h>
#include <math.h>

#define ALPHA 0.1f
#define EPS 1e-6f
#define D 64

// --- degree histograms (per-XCD partials) + position record -----------------
// LOCAL=1: partition by physical XCD, workgroup-scope atomics -> execute in the
// XCD's own L2 (no write-through to the device coherence point). All
// same-address atomics for partition x come from blocks ON XCD x, so the
// per-XCD TCC is the single execution point -> atomicity holds. Kernel-end L2
// writeback publishes the partials (same mechanism every cross-kernel store
// here already relies on).
// LOCAL=0: fallback, plain device-scope atomics, single partition.
template <int LOCAL>
__global__ void count_kernel(const int* __restrict__ src, const int* __restrict__ dst,
                             unsigned* __restrict__ odeg_part, unsigned* __restrict__ ideg_part,
                             unsigned short* __restrict__ pos16, unsigned char* __restrict__ xcc8,
                             int n, int E) {
    int e = blockIdx.x * blockDim.x + threadIdx.x;
    if (e >= E) return;
    int xcc = 0;
    unsigned p;
    if (LOCAL) {
        asm("s_getreg_b32 %0, hwreg(HW_REG_XCC_ID)" : "=s"(xcc));
        xcc &= 7;
        size_t off = (size_t)xcc * n;
        __hip_atomic_fetch_add(&odeg_part[off + src[e]], 1u,
                               __ATOMIC_RELAXED, __HIP_MEMORY_SCOPE_WORKGROUP);
        p = __hip_atomic_fetch_add(&ideg_part[off + dst[e]], 1u,
                                   __ATOMIC_RELAXED, __HIP_MEMORY_SCOPE_WORKGROUP);
    } else {
        atomicAdd(&odeg_part[src[e]], 1u);
        p = atomicAdd(&ideg_part[dst[e]], 1u);
    }
    pos16[e] = (unsigned short)p;
    xcc8[e] = (unsigned char)xcc;
}

// --- sum partials -> degrees -> norms; ideg kept for scan -------------------
__global__ void reduce_norm_kernel(const unsigned* __restrict__ odeg_part,
                                   const unsigned* __restrict__ ideg_part,
                                   float* __restrict__ sn, float* __restrict__ dn,
                                   int* __restrict__ ideg, int n, int NP) {
    int i = blockIdx.x * blockDim.x + threadIdx.x;
    if (i < n) {
        unsigned od = 0, id = 0;
        for (int x = 0; x < NP; ++x) {
            od += odeg_part[(size_t)x * n + i];
            id += ideg_part[(size_t)x * n + i];
        }
        sn[i] = rsqrtf(fmaxf((float)od, 1.0f));
        dn[i] = rsqrtf(fmaxf((float)id, 1.0f));
        ideg[i] = (int)id;
    }
}

// --- exclusive prefix scan of ideg -> rowptr[0..n], single 1024-thread block
__global__ void scan_kernel(const int* __restrict__ ideg, int* __restrict__ rowptr, int n) {
    __shared__ int partials[1024];
    int tid = threadIdx.x;
    int chunk = (n + 1023) / 1024;
    int start = tid * chunk;
    int end = start + chunk < n ? start + chunk : n;
    int sum = 0;
    for (int i = start; i < end; ++i) sum += ideg[i];
    partials[tid] = sum;
    __syncthreads();
    for (int off = 1; off < 1024; off <<= 1) {
        int v = (tid >= off) ? partials[tid - off] : 0;
        __syncthreads();
        partials[tid] += v;
        __syncthreads();
    }
    int running = (tid == 0) ? 0 : partials[tid - 1];  // exclusive
    for (int i = start; i < end; ++i) {
        rowptr[i] = running;
        running += ideg[i];
    }
    if (tid == 1023) rowptr[n] = running;  // == E
}

// --- per-XCD bases: base_part[x][i] = rowptr[i] + sum_{x'<x} ideg_part[x'][i]
// base_part aliases odeg_part (dead after reduce_norm)
__global__ void base_kernel(const int* __restrict__ rowptr, const unsigned* __restrict__ ideg_part,
                            unsigned* __restrict__ base_part, int n, int NP) {
    int i = blockIdx.x * blockDim.x + threadIdx.x;
    if (i < n) {
        unsigned run = (unsigned)rowptr[i];
        for (int x = 0; x < NP; ++x) {
            unsigned c = ideg_part[(size_t)x * n + i];
            base_part[(size_t)x * n + i] = run;
            run += c;
        }
    }
}

// --- atomic-free CSR fill ---------------------------------------------------
__global__ void place_kernel(const int* __restrict__ src, const int* __restrict__ dst,
                             const unsigned short* __restrict__ pos16,
                             const unsigned char* __restrict__ xcc8,
                             const unsigned* __restrict__ base_part,
                             int* __restrict__ csr, int n, int E) {
    int e = blockIdx.x * blockDim.x + threadIdx.x;
    if (e < E) {
        csr[base_part[(size_t)xcc8[e] * n + dst[e]] + pos16[e]] = src[e];
    }
}

// --- seed: scaled_h[row] = feat*sn[row] (f16), pn[row] = sn*||feat[row]|| ---
__global__ void prescale_kernel(const float* __restrict__ feat, const float* __restrict__ sn,
                                __half* __restrict__ outh, float* __restrict__ pn, int n) {
    int row  = blockIdx.x * (blockDim.x >> 6) + (threadIdx.x >> 6);
    int lane = threadIdx.x & 63;
    if (row >= n) return;
    float x = feat[(long)row * D + lane];
    float ss = x * x;
    #pragma unroll
    for (int off = 32; off; off >>= 1) ss += __shfl_xor(ss, off, 64);
    float s = sn[row];
    float v = x * s;
    float vp = __shfl_xor(v, 1, 64);
    if (!(lane & 1)) {
        *(__half2*)(outh + (long)row * D + lane) = __floats2half2_rn(v, vp);
    }
    if (lane == 0) pn[row] = s * sqrtf(ss);
}

// --- fused iteration: one wave per dst row, pure unweighted f16 row sum -----
// lane = (g,sub): g (0..7) = edge slot, sub (0..7) = 16B (8-half) column slice
template <int LAST>
__global__ void iter_kernel(const __half* __restrict__ cur, const float* __restrict__ feat0,
                            const int* __restrict__ rowptr, const int* __restrict__ csr_src,
                            const float* __restrict__ pn, const float* __restrict__ dn,
                            const float* __restrict__ sn,
                            __half* __restrict__ nexth, float* __restrict__ npn,
                            float* __restrict__ out, int n) {
    int row  = blockIdx.x * (blockDim.x >> 6) + (threadIdx.x >> 6);
    int lane = threadIdx.x & 63;
    if (row >= n) return;
    int g = lane >> 3, sub = lane & 7;

    float acc[8] = {0.f, 0.f, 0.f, 0.f, 0.f, 0.f, 0.f, 0.f};
    int beg = rowptr[row], end = rowptr[row + 1];
    for (int base = beg; base < end; base += 64) {
        int m = end - base; if (m > 64) m = 64;
        int s_l = (lane < m) ? csr_src[base + lane] : 0;
        int nj = (m + 7) >> 3;
        for (int j = 0; j < nj; ++j) {
            int e = j * 8 + g;
            int s = __shfl(s_l, e, 64);
            if (e < m) {
                int4 raw = *(const int4*)(cur + (long)s * D + sub * 8);
                float2 f0 = __half22float2(*(__half2*)&raw.x);
                float2 f1 = __half22float2(*(__half2*)&raw.y);
                float2 f2 = __half22float2(*(__half2*)&raw.z);
                float2 f3 = __half22float2(*(__half2*)&raw.w);
                acc[0] += f0.x; acc[1] += f0.y;
                acc[2] += f1.x; acc[3] += f1.y;
                acc[4] += f2.x; acc[5] += f2.y;
                acc[6] += f3.x; acc[7] += f3.y;
            }
        }
    }
    #pragma unroll
    for (int i = 0; i < 8; ++i) {
        float a = acc[i];
        a += __shfl_xor(a, 8, 64);
        a += __shfl_xor(a, 16, 64);
        a += __shfl_xor(a, 32, 64);
        acc[i] = a;
    }
    float dd = 0.f;
    #pragma unroll
    for (int i = 0; i < 8; ++i) dd += acc[i] * acc[i];
    dd += __shfl_xor(dd, 1, 64);
    dd += __shfl_xor(dd, 2, 64);
    dd += __shfl_xor(dd, 4, 64);
    float an = sqrtf(dd);
    float scale = pn[row] / (an + EPS) * dn[row] * (1.0f - ALPHA);

    if (g == 0) {
        long fb = (long)row * D + sub * 8;
        float4 f0a = *(const float4*)(feat0 + fb);
        float4 f0b = *(const float4*)(feat0 + fb + 4);
        float nx[8];
        nx[0] = acc[0] * scale + ALPHA * f0a.x;
        nx[1] = acc[1] * scale + ALPHA * f0a.y;
        nx[2] = acc[2] * scale + ALPHA * f0a.z;
        nx[3] = acc[3] * scale + ALPHA * f0a.w;
        nx[4] = acc[4] * scale + ALPHA * f0b.x;
        nx[5] = acc[5] * scale + ALPHA * f0b.y;
        nx[6] = acc[6] * scale + ALPHA * f0b.z;
        nx[7] = acc[7] * scale + ALPHA * f0b.w;
        if (LAST) {
            float4 o0 = {nx[0], nx[1], nx[2], nx[3]};
            float4 o1 = {nx[4], nx[5], nx[6], nx[7]};
            *(float4*)(out + fb) = o0;
            *(float4*)(out + fb + 4) = o1;
        } else {
            float s = sn[row];
            __half2 h0 = __floats2half2_rn(nx[0] * s, nx[1] * s);
            __half2 h1 = __floats2half2_rn(nx[2] * s, nx[3] * s);
            __half2 h2 = __floats2half2_rn(nx[4] * s, nx[5] * s);
            __half2 h3 = __floats2half2_rn(nx[6] * s, nx[7] * s);
            int4 packed;
            packed.x = *(int*)&h0; packed.y = *(int*)&h1;
            packed.z = *(int*)&h2; packed.w = *(int*)&h3;
            *(int4*)(nexth + fb) = packed;
            float nn = 0.f;
            #pragma unroll
            for (int i = 0; i < 8; ++i) nn += nx[i] * nx[i];
            nn += __shfl_xor(nn, 1, 64);
            nn += __shfl_xor(nn, 2, 64);
            nn += __shfl_xor(nn, 4, 64);
            if (sub == 0) npn[row] = s * sqrtf(nn);
        }
    }
}

extern "C" void kernel_launch(void* const* d_in, const int* in_sizes, int n_in,
                              void* d_out, int out_size, void* d_ws, size_t ws_size,
                              hipStream_t stream) {
    const float* feat = (const float*)d_in[0];
    const int*   src  = (const int*)d_in[1];
    const int*   dst  = (const int*)d_in[2];
    float* out = (float*)d_out;

    int n = in_sizes[0] / D;      // 100000
    int E = in_sizes[1];          // 3200000

    size_t nD2 = (size_t)n * D / 2;   // 4B units of one n*D half-precision buffer

    // choose per-XCD partition count; fall back to 1 if scratch too small
    int NP = 8;
    {
        size_t needW = (size_t)NP * n + 6 * (size_t)n + 8 + (size_t)E + 2 * nD2;
        if (ws_size / 4 < needW) NP = 1;
    }

    // workspace layout (4B units)
    unsigned* odeg_part = (unsigned*)d_ws;                  // NP*n (later: base_part)
    int*   ideg   = (int*)(odeg_part + (size_t)NP * n);     // n
    int*   rowptr = ideg + n;                               // n+8 (n+1 used)
    float* sn     = (float*)(rowptr + n + 8);               // n
    float* dn     = sn + n;                                 // n
    float* pn_a   = dn + n;                                 // n
    float* pn_b   = pn_a + n;                               // n
    int*   csr    = (int*)(pn_b + n);                       // E
    unsigned* regionX = (unsigned*)(csr + E);               // nD2 units
    unsigned* ideg_part = regionX;                          // NP*n (dead before prescale)
    __half*   scaled_a  = (__half*)regionX;                 // n*D halves
    unsigned* regionY   = regionX + nD2;                    // nD2 units
    unsigned short* pos16 = (unsigned short*)regionY;       // E u16 (dead after place)
    unsigned char*  xcc8  = (unsigned char*)(pos16 + E);    // E u8  (dead after place)
    __half*   scaled_b  = (__half*)regionY;                 // n*D halves
    unsigned* base_part = odeg_part;                        // alias, written after reduce

    hipMemsetAsync(odeg_part, 0, (size_t)NP * n * sizeof(unsigned), stream);
    hipMemsetAsync(ideg_part, 0, (size_t)NP * n * sizeof(unsigned), stream);

    int eblocks = (E + 255) / 256;
    int nblocks = (n + 255) / 256;
    if (NP == 8) {
        count_kernel<1><<<eblocks, 256, 0, stream>>>(src, dst, odeg_part, ideg_part,
                                                     pos16, xcc8, n, E);
    } else {
        count_kernel<0><<<eblocks, 256, 0, stream>>>(src, dst, odeg_part, ideg_part,
                                                     pos16, xcc8, n, E);
    }
    reduce_norm_kernel<<<nblocks, 256, 0, stream>>>(odeg_part, ideg_part, sn, dn, ideg, n, NP);
    scan_kernel<<<1, 1024, 0, stream>>>(ideg, rowptr, n);
    base_kernel<<<nblocks, 256, 0, stream>>>(rowptr, ideg_part, base_part, n, NP);
    place_kernel<<<eblocks, 256, 0, stream>>>(src, dst, pos16, xcc8, base_part, csr, n, E);

    int blocks = (n + 3) / 4;  // 4 waves per 256-thread block
    prescale_kernel<<<blocks, 256, 0, stream>>>(feat, sn, scaled_a, pn_a, n);
    iter_kernel<0><<<blocks, 256, 0, stream>>>(scaled_a, feat, rowptr, csr, pn_a, dn, sn,
                                               scaled_b, pn_b, nullptr, n);
    iter_kernel<0><<<blocks, 256, 0, stream>>>(scaled_b, feat, rowptr, csr, pn_b, dn, sn,
                                               scaled_a, pn_a, nullptr, n);
    iter_kernel<1><<<blocks, 256, 0, stream>>>(scaled_a, feat, rowptr, csr, pn_a, dn, sn,
                                               nullptr, nullptr, out, n);
}

// Round 6
// 660.371 us; speedup vs baseline: 1.2097x; 1.2097x over previous
//
#include <hip/hip_runtime.h>
#include <hip/hip_fp16.h>
#include <math.h>

#define ALPHA 0.1f
#define EPS 1e-6f
#define D 64
#define CH 8192      // edges per block in hist/scatter kernels
#define BUCK_SH 8    // 256 nodes per bucket (nbuck = ceil(n/256) must be <= 512)

// --- per-block coarse histograms of dst>>8 and src>>8 (LDS, no global atomics)
__global__ void hist_kernel(const int* __restrict__ src, const int* __restrict__ dst,
                            int* __restrict__ hist_d, int* __restrict__ hist_s,
                            int nbuck, int nblk, int E) {
    __shared__ int hd[512], hs[512];
    int t = threadIdx.x, b = blockIdx.x;
    for (int u = t; u < 512; u += 256) { hd[u] = 0; hs[u] = 0; }
    __syncthreads();
    int beg = b * CH, end = min(beg + CH, E);
    for (int e = beg + t; e < end; e += 256) {
        atomicAdd(&hd[dst[e] >> BUCK_SH], 1);
        atomicAdd(&hs[src[e] >> BUCK_SH], 1);
    }
    __syncthreads();
    for (int u = t; u < nbuck; u += 256) {
        hist_d[u * nblk + b] = hd[u];   // [bucket][block] layout -> linear scan = scatter bases
        hist_s[u * nblk + b] = hs[u];
    }
}

// --- two independent exclusive scans (block 0: d, block 1: s); out[m] = total
__global__ void scan2_kernel(const int* __restrict__ in_d, int* __restrict__ out_d,
                             const int* __restrict__ in_s, int* __restrict__ out_s, int m) {
    __shared__ int partials[1024];
    const int* in  = blockIdx.x ? in_s  : in_d;
    int*       out = blockIdx.x ? out_s : out_d;
    int tid = threadIdx.x;
    int chunk = (m + 1023) / 1024;
    int start = tid * chunk;
    int end = min(start + chunk, m);
    int sum = 0;
    for (int i = start; i < end; ++i) sum += in[i];
    partials[tid] = sum;
    __syncthreads();
    for (int off = 1; off < 1024; off <<= 1) {
        int v = (tid >= off) ? partials[tid - off] : 0;
        __syncthreads();
        partials[tid] += v;
        __syncthreads();
    }
    int running = (tid == 0) ? 0 : partials[tid - 1];
    for (int i = start; i < end; ++i) { out[i] = running; running += in[i]; }
    if (tid == 1023) out[m] = running;   // total == E
}

// --- scatter edges into bucket-grouped arrays (LDS counters, coalesced-ish runs)
__global__ void scatter_kernel(const int* __restrict__ src, const int* __restrict__ dst,
                               const int* __restrict__ sbase_d, const int* __restrict__ sbase_s,
                               int2* __restrict__ pairs, int* __restrict__ skeys,
                               int nbuck, int nblk, int E) {
    __shared__ int cd[512], cs[512];
    int t = threadIdx.x, b = blockIdx.x;
    for (int u = t; u < nbuck; u += 256) {
        cd[u] = sbase_d[u * nblk + b];
        cs[u] = sbase_s[u * nblk + b];
    }
    __syncthreads();
    int beg = b * CH, end = min(beg + CH, E);
    for (int e = beg + t; e < end; e += 256) {
        int dv = dst[e], sv = src[e];
        int pu = atomicAdd(&cd[dv >> BUCK_SH], 1);
        pairs[pu] = make_int2(dv, sv);
        int su = atomicAdd(&cs[sv >> BUCK_SH], 1);
        skeys[su] = sv;
    }
}

// --- per-bucket src-degree count -> sn (one block per 256-node bucket) ------
__global__ void src_deg_kernel(const int* __restrict__ skeys, const int* __restrict__ sbase_s,
                               float* __restrict__ sn, int nbuck, int nblk, int n) {
    __shared__ int lh[256];
    int t = threadIdx.x, u = blockIdx.x;
    lh[t] = 0;
    __syncthreads();
    int beg = sbase_s[u * nblk];
    int end = sbase_s[(u + 1) * nblk];   // u+1==nbuck -> index m -> total
    for (int i = beg + t; i < end; i += 256) atomicAdd(&lh[skeys[i] & 255], 1);
    __syncthreads();
    int node = (u << BUCK_SH) + t;
    if (node < n) sn[node] = rsqrtf(fmaxf((float)lh[t], 1.0f));
}

// --- per-bucket dst-side build: ideg->dn, rowptr, csr fill (all in LDS) -----
__global__ void build_kernel(const int2* __restrict__ pairs, const int* __restrict__ sbase_d,
                             int* __restrict__ rowptr, int* __restrict__ csr,
                             float* __restrict__ dn, int nbuck, int nblk, int n, int E) {
    __shared__ int lh[256], le[256], cnt[256];
    int t = threadIdx.x, u = blockIdx.x;
    lh[t] = 0; cnt[t] = 0;
    __syncthreads();
    int beg = sbase_d[u * nblk];
    int end = sbase_d[(u + 1) * nblk];
    for (int i = beg + t; i < end; i += 256) atomicAdd(&lh[pairs[i].x & 255], 1);
    __syncthreads();
    int c0 = lh[t];
    for (int off = 1; off < 256; off <<= 1) {   // inclusive Hillis-Steele in LDS
        int x = (t >= off) ? lh[t - off] : 0;
        __syncthreads();
        lh[t] += x;
        __syncthreads();
    }
    le[t] = lh[t] - c0;                          // exclusive prefix within bucket
    __syncthreads();
    int node = (u << BUCK_SH) + t;
    if (node < n) {
        rowptr[node] = beg + le[t];
        dn[node] = rsqrtf(fmaxf((float)c0, 1.0f));
    }
    if (u == nbuck - 1 && t == 0) rowptr[n] = E;
    for (int i = beg + t; i < end; i += 256) {
        int2 pr = pairs[i];
        int bb = pr.x & 255;
        int p = atomicAdd(&cnt[bb], 1);
        csr[beg + le[bb] + p] = pr.y;
    }
}

// --- seed: scaled_h[row] = feat*sn[row] (f16), pn[row] = sn*||feat[row]|| ---
__global__ void prescale_kernel(const float* __restrict__ feat, const float* __restrict__ sn,
                                __half* __restrict__ outh, float* __restrict__ pn, int n) {
    int row  = blockIdx.x * (blockDim.x >> 6) + (threadIdx.x >> 6);
    int lane = threadIdx.x & 63;
    if (row >= n) return;
    float x = feat[(long)row * D + lane];
    float ss = x * x;
    #pragma unroll
    for (int off = 32; off; off >>= 1) ss += __shfl_xor(ss, off, 64);
    float s = sn[row];
    float v = x * s;
    float vp = __shfl_xor(v, 1, 64);
    if (!(lane & 1)) {
        *(__half2*)(outh + (long)row * D + lane) = __floats2half2_rn(v, vp);
    }
    if (lane == 0) pn[row] = s * sqrtf(ss);
}

// --- fused iteration: one wave per dst row, pure unweighted f16 row sum -----
// lane = (g,sub): g (0..7) = edge slot, sub (0..7) = 16B (8-half) column slice
template <int LAST>
__global__ void iter_kernel(const __half* __restrict__ cur, const float* __restrict__ feat0,
                            const int* __restrict__ rowptr, const int* __restrict__ csr_src,
                            const float* __restrict__ pn, const float* __restrict__ dn,
                            const float* __restrict__ sn,
                            __half* __restrict__ nexth, float* __restrict__ npn,
                            float* __restrict__ out, int n) {
    int row  = blockIdx.x * (blockDim.x >> 6) + (threadIdx.x >> 6);
    int lane = threadIdx.x & 63;
    if (row >= n) return;
    int g = lane >> 3, sub = lane & 7;

    float acc[8] = {0.f, 0.f, 0.f, 0.f, 0.f, 0.f, 0.f, 0.f};
    int beg = rowptr[row], end = rowptr[row + 1];
    for (int base = beg; base < end; base += 64) {
        int m = end - base; if (m > 64) m = 64;
        int s_l = (lane < m) ? csr_src[base + lane] : 0;
        int nj = (m + 7) >> 3;
        for (int j = 0; j < nj; ++j) {
            int e = j * 8 + g;
            int s = __shfl(s_l, e, 64);
            if (e < m) {
                int4 raw = *(const int4*)(cur + (long)s * D + sub * 8);
                float2 f0 = __half22float2(*(__half2*)&raw.x);
                float2 f1 = __half22float2(*(__half2*)&raw.y);
                float2 f2 = __half22float2(*(__half2*)&raw.z);
                float2 f3 = __half22float2(*(__half2*)&raw.w);
                acc[0] += f0.x; acc[1] += f0.y;
                acc[2] += f1.x; acc[3] += f1.y;
                acc[4] += f2.x; acc[5] += f2.y;
                acc[6] += f3.x; acc[7] += f3.y;
            }
        }
    }
    #pragma unroll
    for (int i = 0; i < 8; ++i) {
        float a = acc[i];
        a += __shfl_xor(a, 8, 64);
        a += __shfl_xor(a, 16, 64);
        a += __shfl_xor(a, 32, 64);
        acc[i] = a;
    }
    float dd = 0.f;
    #pragma unroll
    for (int i = 0; i < 8; ++i) dd += acc[i] * acc[i];
    dd += __shfl_xor(dd, 1, 64);
    dd += __shfl_xor(dd, 2, 64);
    dd += __shfl_xor(dd, 4, 64);
    float an = sqrtf(dd);
    float scale = pn[row] / (an + EPS) * dn[row] * (1.0f - ALPHA);

    if (g == 0) {
        long fb = (long)row * D + sub * 8;
        float4 f0a = *(const float4*)(feat0 + fb);
        float4 f0b = *(const float4*)(feat0 + fb + 4);
        float nx[8];
        nx[0] = acc[0] * scale + ALPHA * f0a.x;
        nx[1] = acc[1] * scale + ALPHA * f0a.y;
        nx[2] = acc[2] * scale + ALPHA * f0a.z;
        nx[3] = acc[3] * scale + ALPHA * f0a.w;
        nx[4] = acc[4] * scale + ALPHA * f0b.x;
        nx[5] = acc[5] * scale + ALPHA * f0b.y;
        nx[6] = acc[6] * scale + ALPHA * f0b.z;
        nx[7] = acc[7] * scale + ALPHA * f0b.w;
        if (LAST) {
            float4 o0 = {nx[0], nx[1], nx[2], nx[3]};
            float4 o1 = {nx[4], nx[5], nx[6], nx[7]};
            *(float4*)(out + fb) = o0;
            *(float4*)(out + fb + 4) = o1;
        } else {
            float s = sn[row];
            __half2 h0 = __floats2half2_rn(nx[0] * s, nx[1] * s);
            __half2 h1 = __floats2half2_rn(nx[2] * s, nx[3] * s);
            __half2 h2 = __floats2half2_rn(nx[4] * s, nx[5] * s);
            __half2 h3 = __floats2half2_rn(nx[6] * s, nx[7] * s);
            int4 packed;
            packed.x = *(int*)&h0; packed.y = *(int*)&h1;
            packed.z = *(int*)&h2; packed.w = *(int*)&h3;
            *(int4*)(nexth + fb) = packed;
            float nn = 0.f;
            #pragma unroll
            for (int i = 0; i < 8; ++i) nn += nx[i] * nx[i];
            nn += __shfl_xor(nn, 1, 64);
            nn += __shfl_xor(nn, 2, 64);
            nn += __shfl_xor(nn, 4, 64);
            if (sub == 0) npn[row] = s * sqrtf(nn);
        }
    }
}

extern "C" void kernel_launch(void* const* d_in, const int* in_sizes, int n_in,
                              void* d_out, int out_size, void* d_ws, size_t ws_size,
                              hipStream_t stream) {
    const float* feat = (const float*)d_in[0];
    const int*   src  = (const int*)d_in[1];
    const int*   dst  = (const int*)d_in[2];
    float* out = (float*)d_out;

    int n = in_sizes[0] / D;      // 100000
    int E = in_sizes[1];          // 3200000

    int nbuck = (n + 255) >> BUCK_SH;        // 391 (<= 512 required)
    int nblk  = (E + CH - 1) / CH;           // 391
    int m     = nbuck * nblk;

    // workspace layout (4B units)
    int* hist_d  = (int*)d_ws;               // m
    int* hist_s  = hist_d + m;               // m
    int* sbase_d = hist_s + m;               // m+1
    int* sbase_s = sbase_d + m + 1;          // m+1
    int* rowptr  = sbase_s + m + 1;          // n+1
    float* sn    = (float*)(rowptr + n + 1); // n
    float* dn    = sn + n;                   // n
    float* pn_a  = dn + n;                   // n
    float* pn_b  = pn_a + n;                 // n
    // region P: pairs (2E u32), later aliased by the two f16 ping-pong buffers (n*D u32)
    size_t offP  = (size_t)(4 * m + 2) + 5 * (size_t)n + 1;
    offP = (offP + 3) & ~(size_t)3;          // 16B align
    int2*   pairs    = (int2*)((int*)d_ws + offP);
    size_t  szP      = 2 * (size_t)E > (size_t)n * D ? 2 * (size_t)E : (size_t)n * D;
    __half* scaled_a = (__half*)pairs;                  // n*D halves (alias P)
    __half* scaled_b = scaled_a + (size_t)n * D;        // n*D halves (alias P)
    // region Q: skeys (E u32), later aliased by csr (E u32)
    int* skeys = (int*)d_ws + offP + szP;
    int* csr   = skeys;

    int eblocks = nblk;
    // 1. coarse histograms (no global atomics)
    hist_kernel<<<eblocks, 256, 0, stream>>>(src, dst, hist_d, hist_s, nbuck, nblk, E);
    // 2. exclusive scans of both [bucket][block] matrices
    scan2_kernel<<<2, 1024, 0, stream>>>(hist_d, sbase_d, hist_s, sbase_s, m);
    // 3. scatter edges into bucket-grouped arrays
    scatter_kernel<<<eblocks, 256, 0, stream>>>(src, dst, sbase_d, sbase_s, pairs, skeys,
                                                nbuck, nblk, E);
    // 4. src-side per-node degree -> sn   (skeys consumed here)
    src_deg_kernel<<<nbuck, 256, 0, stream>>>(skeys, sbase_s, sn, nbuck, nblk, n);
    // 5. dst-side build: rowptr, dn, csr  (csr aliases skeys; pairs consumed here)
    build_kernel<<<nbuck, 256, 0, stream>>>(pairs, sbase_d, rowptr, csr, dn, nbuck, nblk, n, E);

    // 6. propagation: prescale + 3 fused iterations (f16 ping-pong aliases pairs)
    int blocks = (n + 3) / 4;  // 4 waves per 256-thread block
    prescale_kernel<<<blocks, 256, 0, stream>>>(feat, sn, scaled_a, pn_a, n);
    iter_kernel<0><<<blocks, 256, 0, stream>>>(scaled_a, feat, rowptr, csr, pn_a, dn, sn,
                                               scaled_b, pn_b, nullptr, n);
    iter_kernel<0><<<blocks, 256, 0, stream>>>(scaled_b, feat, rowptr, csr, pn_b, dn, sn,
                                               scaled_a, pn_a, nullptr, n);
    iter_kernel<1><<<blocks, 256, 0, stream>>>(scaled_a, feat, rowptr, csr, pn_a, dn, sn,
                                               nullptr, nullptr, out, n);
}

// Round 7
// 422.217 us; speedup vs baseline: 1.8921x; 1.5641x over previous
//
#include <hip/hip_runtime.h>
#include <hip/hip_fp16.h>
#include <math.h>

#define ALPHA 0.1f
#define EPS 1e-6f
#define D 64
#define CH 8192      // edges per block in hist/scatter kernels
#define BUCK_SH 8    // 256 nodes per bucket (nbuck = ceil(n/256) must be <= 512)

// --- per-block coarse histograms of dst>>8 and src>>8 (LDS, no global atomics)
__global__ void hist_kernel(const int* __restrict__ src, const int* __restrict__ dst,
                            int* __restrict__ hist_d, int* __restrict__ hist_s,
                            int nbuck, int nblk, int E) {
    __shared__ int hd[512], hs[512];
    int t = threadIdx.x, b = blockIdx.x;
    for (int u = t; u < 512; u += 256) { hd[u] = 0; hs[u] = 0; }
    __syncthreads();
    int beg = b * CH, end = min(beg + CH, E);
    for (int e = beg + t; e < end; e += 256) {
        atomicAdd(&hd[dst[e] >> BUCK_SH], 1);
        atomicAdd(&hs[src[e] >> BUCK_SH], 1);
    }
    __syncthreads();
    for (int u = t; u < nbuck; u += 256) {
        hist_d[u * nblk + b] = hd[u];   // [bucket][block] layout
        hist_s[u * nblk + b] = hs[u];
    }
}

// --- stage 1: per-bucket totals (one block per bucket, coalesced row sum) ---
__global__ void bucket_total_kernel(const int* __restrict__ hist_d, const int* __restrict__ hist_s,
                                    int* __restrict__ tot_d, int* __restrict__ tot_s, int nblk) {
    __shared__ int rd[256], rs[256];
    int u = blockIdx.x, t = threadIdx.x;
    int sd = 0, ss = 0;
    for (int b = t; b < nblk; b += 256) {
        sd += hist_d[u * nblk + b];
        ss += hist_s[u * nblk + b];
    }
    rd[t] = sd; rs[t] = ss;
    __syncthreads();
    for (int off = 128; off; off >>= 1) {
        if (t < off) { rd[t] += rd[t + off]; rs[t] += rs[t + off]; }
        __syncthreads();
    }
    if (t == 0) { tot_d[u] = rd[0]; tot_s[u] = rs[0]; }
}

// --- stage 2: exclusive scan of bucket totals (single 512-thread block) -----
__global__ void base_scan_kernel(const int* __restrict__ tot_d, const int* __restrict__ tot_s,
                                 int* __restrict__ base_d, int* __restrict__ base_s, int nbuck) {
    __shared__ int a[512], b[512];
    int t = threadIdx.x;
    int vd = (t < nbuck) ? tot_d[t] : 0;
    int vs = (t < nbuck) ? tot_s[t] : 0;
    a[t] = vd; b[t] = vs;
    __syncthreads();
    for (int off = 1; off < 512; off <<= 1) {
        int av = (t >= off) ? a[t - off] : 0;
        int bv = (t >= off) ? b[t - off] : 0;
        __syncthreads();
        a[t] += av; b[t] += bv;
        __syncthreads();
    }
    if (t < nbuck) {
        base_d[t] = a[t] - vd;   // exclusive
        base_s[t] = b[t] - vs;
    }
}

// --- stage 3: per-bucket row scan + bucket base -> scatter bases ------------
__global__ void row_scan_kernel(const int* __restrict__ hist_d, const int* __restrict__ hist_s,
                                const int* __restrict__ base_d, const int* __restrict__ base_s,
                                int* __restrict__ sbase_d, int* __restrict__ sbase_s,
                                int nblk, int E, int m) {
    __shared__ int a[512], b[512];
    int u = blockIdx.x, t = threadIdx.x;
    int hd = (t < nblk) ? hist_d[u * nblk + t] : 0;
    int hs = (t < nblk) ? hist_s[u * nblk + t] : 0;
    a[t] = hd; b[t] = hs;
    __syncthreads();
    for (int off = 1; off < 512; off <<= 1) {
        int av = (t >= off) ? a[t - off] : 0;
        int bv = (t >= off) ? b[t - off] : 0;
        __syncthreads();
        a[t] += av; b[t] += bv;
        __syncthreads();
    }
    if (t < nblk) {
        sbase_d[u * nblk + t] = base_d[u] + a[t] - hd;
        sbase_s[u * nblk + t] = base_s[u] + b[t] - hs;
    }
    if (u == 0 && t == 0) { sbase_d[m] = E; sbase_s[m] = E; }
}

// --- scatter edges into bucket-grouped arrays (LDS counters) ----------------
__global__ void scatter_kernel(const int* __restrict__ src, const int* __restrict__ dst,
                               const int* __restrict__ sbase_d, const int* __restrict__ sbase_s,
                               int2* __restrict__ pairs, int* __restrict__ skeys,
                               int nbuck, int nblk, int E) {
    __shared__ int cd[512], cs[512];
    int t = threadIdx.x, b = blockIdx.x;
    for (int u = t; u < nbuck; u += 256) {
        cd[u] = sbase_d[u * nblk + b];
        cs[u] = sbase_s[u * nblk + b];
    }
    __syncthreads();
    int beg = b * CH, end = min(beg + CH, E);
    for (int e = beg + t; e < end; e += 256) {
        int dv = dst[e], sv = src[e];
        int pu = atomicAdd(&cd[dv >> BUCK_SH], 1);
        pairs[pu] = make_int2(dv, sv);
        int su = atomicAdd(&cs[sv >> BUCK_SH], 1);
        skeys[su] = sv;
    }
}

// --- per-bucket src-degree count -> sn (one block per 256-node bucket) ------
__global__ void src_deg_kernel(const int* __restrict__ skeys, const int* __restrict__ sbase_s,
                               float* __restrict__ sn, int nbuck, int nblk, int n) {
    __shared__ int lh[256];
    int t = threadIdx.x, u = blockIdx.x;
    lh[t] = 0;
    __syncthreads();
    int beg = sbase_s[u * nblk];
    int end = sbase_s[(u + 1) * nblk];   // u+1==nbuck -> index m -> E
    for (int i = beg + t; i < end; i += 256) atomicAdd(&lh[skeys[i] & 255], 1);
    __syncthreads();
    int node = (u << BUCK_SH) + t;
    if (node < n) sn[node] = rsqrtf(fmaxf((float)lh[t], 1.0f));
}

// --- per-bucket dst-side build: ideg->dn, rowptr, csr fill (all in LDS) -----
__global__ void build_kernel(const int2* __restrict__ pairs, const int* __restrict__ sbase_d,
                             int* __restrict__ rowptr, int* __restrict__ csr,
                             float* __restrict__ dn, int nbuck, int nblk, int n, int E) {
    __shared__ int lh[256], le[256], cnt[256];
    int t = threadIdx.x, u = blockIdx.x;
    lh[t] = 0; cnt[t] = 0;
    __syncthreads();
    int beg = sbase_d[u * nblk];
    int end = sbase_d[(u + 1) * nblk];
    for (int i = beg + t; i < end; i += 256) atomicAdd(&lh[pairs[i].x & 255], 1);
    __syncthreads();
    int c0 = lh[t];
    for (int off = 1; off < 256; off <<= 1) {
        int x = (t >= off) ? lh[t - off] : 0;
        __syncthreads();
        lh[t] += x;
        __syncthreads();
    }
    le[t] = lh[t] - c0;
    __syncthreads();
    int node = (u << BUCK_SH) + t;
    if (node < n) {
        rowptr[node] = beg + le[t];
        dn[node] = rsqrtf(fmaxf((float)c0, 1.0f));
    }
    if (u == nbuck - 1 && t == 0) rowptr[n] = E;
    for (int i = beg + t; i < end; i += 256) {
        int2 pr = pairs[i];
        int bb = pr.x & 255;
        int p = atomicAdd(&cnt[bb], 1);
        csr[beg + le[bb] + p] = pr.y;
    }
}

// --- seed: scaled_h[row] = feat*sn[row] (f16), pn[row] = sn*||feat[row]|| ---
__global__ void prescale_kernel(const float* __restrict__ feat, const float* __restrict__ sn,
                                __half* __restrict__ outh, float* __restrict__ pn, int n) {
    int row  = blockIdx.x * (blockDim.x >> 6) + (threadIdx.x >> 6);
    int lane = threadIdx.x & 63;
    if (row >= n) return;
    float x = feat[(long)row * D + lane];
    float ss = x * x;
    #pragma unroll
    for (int off = 32; off; off >>= 1) ss += __shfl_xor(ss, off, 64);
    float s = sn[row];
    float v = x * s;
    float vp = __shfl_xor(v, 1, 64);
    if (!(lane & 1)) {
        *(__half2*)(outh + (long)row * D + lane) = __floats2half2_rn(v, vp);
    }
    if (lane == 0) pn[row] = s * sqrtf(ss);
}

// --- fused iteration: one wave per dst row, pure unweighted f16 row sum -----
template <int LAST>
__global__ void iter_kernel(const __half* __restrict__ cur, const float* __restrict__ feat0,
                            const int* __restrict__ rowptr, const int* __restrict__ csr_src,
                            const float* __restrict__ pn, const float* __restrict__ dn,
                            const float* __restrict__ sn,
                            __half* __restrict__ nexth, float* __restrict__ npn,
                            float* __restrict__ out, int n) {
    int row  = blockIdx.x * (blockDim.x >> 6) + (threadIdx.x >> 6);
    int lane = threadIdx.x & 63;
    if (row >= n) return;
    int g = lane >> 3, sub = lane & 7;

    float acc[8] = {0.f, 0.f, 0.f, 0.f, 0.f, 0.f, 0.f, 0.f};
    int beg = rowptr[row], end = rowptr[row + 1];
    for (int base = beg; base < end; base += 64) {
        int m = end - base; if (m > 64) m = 64;
        int s_l = (lane < m) ? csr_src[base + lane] : 0;
        int nj = (m + 7) >> 3;
        for (int j = 0; j < nj; ++j) {
            int e = j * 8 + g;
            int s = __shfl(s_l, e, 64);
            if (e < m) {
                int4 raw = *(const int4*)(cur + (long)s * D + sub * 8);
                float2 f0 = __half22float2(*(__half2*)&raw.x);
                float2 f1 = __half22float2(*(__half2*)&raw.y);
                float2 f2 = __half22float2(*(__half2*)&raw.z);
                float2 f3 = __half22float2(*(__half2*)&raw.w);
                acc[0] += f0.x; acc[1] += f0.y;
                acc[2] += f1.x; acc[3] += f1.y;
                acc[4] += f2.x; acc[5] += f2.y;
                acc[6] += f3.x; acc[7] += f3.y;
            }
        }
    }
    #pragma unroll
    for (int i = 0; i < 8; ++i) {
        float a = acc[i];
        a += __shfl_xor(a, 8, 64);
        a += __shfl_xor(a, 16, 64);
        a += __shfl_xor(a, 32, 64);
        acc[i] = a;
    }
    float dd = 0.f;
    #pragma unroll
    for (int i = 0; i < 8; ++i) dd += acc[i] * acc[i];
    dd += __shfl_xor(dd, 1, 64);
    dd += __shfl_xor(dd, 2, 64);
    dd += __shfl_xor(dd, 4, 64);
    float an = sqrtf(dd);
    float scale = pn[row] / (an + EPS) * dn[row] * (1.0f - ALPHA);

    if (g == 0) {
        long fb = (long)row * D + sub * 8;
        float4 f0a = *(const float4*)(feat0 + fb);
        float4 f0b = *(const float4*)(feat0 + fb + 4);
        float nx[8];
        nx[0] = acc[0] * scale + ALPHA * f0a.x;
        nx[1] = acc[1] * scale + ALPHA * f0a.y;
        nx[2] = acc[2] * scale + ALPHA * f0a.z;
        nx[3] = acc[3] * scale + ALPHA * f0a.w;
        nx[4] = acc[4] * scale + ALPHA * f0b.x;
        nx[5] = acc[5] * scale + ALPHA * f0b.y;
        nx[6] = acc[6] * scale + ALPHA * f0b.z;
        nx[7] = acc[7] * scale + ALPHA * f0b.w;
        if (LAST) {
            float4 o0 = {nx[0], nx[1], nx[2], nx[3]};
            float4 o1 = {nx[4], nx[5], nx[6], nx[7]};
            *(float4*)(out + fb) = o0;
            *(float4*)(out + fb + 4) = o1;
        } else {
            float s = sn[row];
            __half2 h0 = __floats2half2_rn(nx[0] * s, nx[1] * s);
            __half2 h1 = __floats2half2_rn(nx[2] * s, nx[3] * s);
            __half2 h2 = __floats2half2_rn(nx[4] * s, nx[5] * s);
            __half2 h3 = __floats2half2_rn(nx[6] * s, nx[7] * s);
            int4 packed;
            packed.x = *(int*)&h0; packed.y = *(int*)&h1;
            packed.z = *(int*)&h2; packed.w = *(int*)&h3;
            *(int4*)(nexth + fb) = packed;
            float nn = 0.f;
            #pragma unroll
            for (int i = 0; i < 8; ++i) nn += nx[i] * nx[i];
            nn += __shfl_xor(nn, 1, 64);
            nn += __shfl_xor(nn, 2, 64);
            nn += __shfl_xor(nn, 4, 64);
            if (sub == 0) npn[row] = s * sqrtf(nn);
        }
    }
}

extern "C" void kernel_launch(void* const* d_in, const int* in_sizes, int n_in,
                              void* d_out, int out_size, void* d_ws, size_t ws_size,
                              hipStream_t stream) {
    const float* feat = (const float*)d_in[0];
    const int*   src  = (const int*)d_in[1];
    const int*   dst  = (const int*)d_in[2];
    float* out = (float*)d_out;

    int n = in_sizes[0] / D;      // 100000
    int E = in_sizes[1];          // 3200000

    int nbuck = (n + 255) >> BUCK_SH;        // 391 (<= 512 required)
    int nblk  = (E + CH - 1) / CH;           // 391 (<= 512 required)
    int m     = nbuck * nblk;

    // workspace layout (4B units)
    int* hist_d  = (int*)d_ws;               // m
    int* hist_s  = hist_d + m;               // m
    int* sbase_d = hist_s + m;               // m+1
    int* sbase_s = sbase_d + m + 1;          // m+1
    int* tot_d   = sbase_s + m + 1;          // 512
    int* tot_s   = tot_d + 512;              // 512
    int* base_d  = tot_s + 512;              // 512
    int* base_s  = base_d + 512;             // 512
    int* rowptr  = base_s + 512;             // n+1
    float* sn    = (float*)(rowptr + n + 1); // n
    float* dn    = sn + n;                   // n
    float* pn_a  = dn + n;                   // n
    float* pn_b  = pn_a + n;                 // n
    // region P: pairs (2E u32), later aliased by the two f16 ping-pong buffers
    size_t offP  = (size_t)(4 * m + 2) + 2048 + 5 * (size_t)n + 1;
    offP = (offP + 3) & ~(size_t)3;          // 16B align
    int2*   pairs    = (int2*)((int*)d_ws + offP);
    size_t  szP      = 2 * (size_t)E > (size_t)n * D ? 2 * (size_t)E : (size_t)n * D;
    __half* scaled_a = (__half*)pairs;                  // n*D halves (alias P)
    __half* scaled_b = scaled_a + (size_t)n * D;        // n*D halves (alias P)
    // region Q: skeys (E u32), later aliased by csr (E u32)
    int* skeys = (int*)d_ws + offP + szP;
    int* csr   = skeys;

    int eblocks = nblk;
    // 1. coarse histograms (no global atomics)
    hist_kernel<<<eblocks, 256, 0, stream>>>(src, dst, hist_d, hist_s, nbuck, nblk, E);
    // 2. hierarchical exclusive scan of both [bucket][block] matrices
    bucket_total_kernel<<<nbuck, 256, 0, stream>>>(hist_d, hist_s, tot_d, tot_s, nblk);
    base_scan_kernel<<<1, 512, 0, stream>>>(tot_d, tot_s, base_d, base_s, nbuck);
    row_scan_kernel<<<nbuck, 512, 0, stream>>>(hist_d, hist_s, base_d, base_s,
                                               sbase_d, sbase_s, nblk, E, m);
    // 3. scatter edges into bucket-grouped arrays
    scatter_kernel<<<eblocks, 256, 0, stream>>>(src, dst, sbase_d, sbase_s, pairs, skeys,
                                                nbuck, nblk, E);
    // 4. src-side per-node degree -> sn   (skeys consumed here)
    src_deg_kernel<<<nbuck, 256, 0, stream>>>(skeys, sbase_s, sn, nbuck, nblk, n);
    // 5. dst-side build: rowptr, dn, csr  (csr aliases skeys; pairs consumed here)
    build_kernel<<<nbuck, 256, 0, stream>>>(pairs, sbase_d, rowptr, csr, dn, nbuck, nblk, n, E);

    // 6. propagation: prescale + 3 fused iterations (f16 ping-pong aliases pairs)
    int blocks = (n + 3) / 4;  // 4 waves per 256-thread block
    prescale_kernel<<<blocks, 256, 0, stream>>>(feat, sn, scaled_a, pn_a, n);
    iter_kernel<0><<<blocks, 256, 0, stream>>>(scaled_a, feat, rowptr, csr, pn_a, dn, sn,
                                               scaled_b, pn_b, nullptr, n);
    iter_kernel<0><<<blocks, 256, 0, stream>>>(scaled_b, feat, rowptr, csr, pn_b, dn, sn,
                                               scaled_a, pn_a, nullptr, n);
    iter_kernel<1><<<blocks, 256, 0, stream>>>(scaled_a, feat, rowptr, csr, pn_a, dn, sn,
                                               nullptr, nullptr, out, n);
}

// Round 8
// 336.546 us; speedup vs baseline: 2.3737x; 1.2546x over previous
//
#include <hip/hip_runtime.h>
#include <hip/hip_fp16.h>
#include <math.h>

#define ALPHA 0.1f
#define EPS 1e-6f
#define D 64
#define CH 8192      // edges per block in hist/scatter kernels
#define BUCK_SH 8    // 256 nodes per bucket (nbuck = ceil(n/256) must be <= 512)

// --- per-block coarse histograms of dst>>8 and src>>8 (LDS, no global atomics)
__global__ void hist_kernel(const int* __restrict__ src, const int* __restrict__ dst,
                            int* __restrict__ hist_d, int* __restrict__ hist_s,
                            int nbuck, int nblk, int E) {
    __shared__ int hd[512], hs[512];
    int t = threadIdx.x, b = blockIdx.x;
    for (int u = t; u < 512; u += 256) { hd[u] = 0; hs[u] = 0; }
    __syncthreads();
    int beg = b * CH, end = min(beg + CH, E);
    for (int e = beg + t; e < end; e += 256) {
        atomicAdd(&hd[dst[e] >> BUCK_SH], 1);
        atomicAdd(&hs[src[e] >> BUCK_SH], 1);
    }
    __syncthreads();
    for (int u = t; u < nbuck; u += 256) {
        hist_d[u * nblk + b] = hd[u];   // [bucket][block] layout
        hist_s[u * nblk + b] = hs[u];
    }
}

// --- stage 1: per-bucket totals (one block per bucket, coalesced row sum) ---
__global__ void bucket_total_kernel(const int* __restrict__ hist_d, const int* __restrict__ hist_s,
                                    int* __restrict__ tot_d, int* __restrict__ tot_s, int nblk) {
    __shared__ int rd[256], rs[256];
    int u = blockIdx.x, t = threadIdx.x;
    int sd = 0, ss = 0;
    for (int b = t; b < nblk; b += 256) {
        sd += hist_d[u * nblk + b];
        ss += hist_s[u * nblk + b];
    }
    rd[t] = sd; rs[t] = ss;
    __syncthreads();
    for (int off = 128; off; off >>= 1) {
        if (t < off) { rd[t] += rd[t + off]; rs[t] += rs[t + off]; }
        __syncthreads();
    }
    if (t == 0) { tot_d[u] = rd[0]; tot_s[u] = rs[0]; }
}

// --- stage 2: exclusive scan of bucket totals (single 512-thread block) -----
__global__ void base_scan_kernel(const int* __restrict__ tot_d, const int* __restrict__ tot_s,
                                 int* __restrict__ base_d, int* __restrict__ base_s, int nbuck) {
    __shared__ int a[512], b[512];
    int t = threadIdx.x;
    int vd = (t < nbuck) ? tot_d[t] : 0;
    int vs = (t < nbuck) ? tot_s[t] : 0;
    a[t] = vd; b[t] = vs;
    __syncthreads();
    for (int off = 1; off < 512; off <<= 1) {
        int av = (t >= off) ? a[t - off] : 0;
        int bv = (t >= off) ? b[t - off] : 0;
        __syncthreads();
        a[t] += av; b[t] += bv;
        __syncthreads();
    }
    if (t < nbuck) {
        base_d[t] = a[t] - vd;   // exclusive
        base_s[t] = b[t] - vs;
    }
}

// --- stage 3: per-bucket row scan + bucket base -> scatter bases ------------
__global__ void row_scan_kernel(const int* __restrict__ hist_d, const int* __restrict__ hist_s,
                                const int* __restrict__ base_d, const int* __restrict__ base_s,
                                int* __restrict__ sbase_d, int* __restrict__ sbase_s,
                                int nblk, int E, int m) {
    __shared__ int a[512], b[512];
    int u = blockIdx.x, t = threadIdx.x;
    int hd = (t < nblk) ? hist_d[u * nblk + t] : 0;
    int hs = (t < nblk) ? hist_s[u * nblk + t] : 0;
    a[t] = hd; b[t] = hs;
    __syncthreads();
    for (int off = 1; off < 512; off <<= 1) {
        int av = (t >= off) ? a[t - off] : 0;
        int bv = (t >= off) ? b[t - off] : 0;
        __syncthreads();
        a[t] += av; b[t] += bv;
        __syncthreads();
    }
    if (t < nblk) {
        sbase_d[u * nblk + t] = base_d[u] + a[t] - hd;
        sbase_s[u * nblk + t] = base_s[u] + b[t] - hs;
    }
    if (u == 0 && t == 0) { sbase_d[m] = E; sbase_s[m] = E; }
}

// --- scatter edges into bucket-grouped arrays (LDS counters) ----------------
// pairs packed: (dst & 255) << 24 | src   (requires n < 2^24)
__global__ void scatter_kernel(const int* __restrict__ src, const int* __restrict__ dst,
                               const int* __restrict__ sbase_d, const int* __restrict__ sbase_s,
                               unsigned* __restrict__ pairs, unsigned char* __restrict__ skeys,
                               int nbuck, int nblk, int E) {
    __shared__ int cd[512], cs[512];
    int t = threadIdx.x, b = blockIdx.x;
    for (int u = t; u < nbuck; u += 256) {
        cd[u] = sbase_d[u * nblk + b];
        cs[u] = sbase_s[u * nblk + b];
    }
    __syncthreads();
    int beg = b * CH, end = min(beg + CH, E);
    for (int e = beg + t; e < end; e += 256) {
        int dv = dst[e], sv = src[e];
        int pu = atomicAdd(&cd[dv >> BUCK_SH], 1);
        pairs[pu] = ((unsigned)(dv & 255) << 24) | (unsigned)sv;
        int su = atomicAdd(&cs[sv >> BUCK_SH], 1);
        skeys[su] = (unsigned char)(sv & 255);
    }
}

// --- per-bucket src-degree count -> sn (one block per 256-node bucket) ------
__global__ void src_deg_kernel(const unsigned char* __restrict__ skeys,
                               const int* __restrict__ sbase_s,
                               float* __restrict__ sn, int nbuck, int nblk, int n) {
    __shared__ int lh[256];
    int t = threadIdx.x, u = blockIdx.x;
    lh[t] = 0;
    __syncthreads();
    int beg = sbase_s[u * nblk];
    int end = sbase_s[(u + 1) * nblk];   // u+1==nbuck -> index m -> E
    for (int i = beg + t; i < end; i += 256) atomicAdd(&lh[skeys[i]], 1);
    __syncthreads();
    int node = (u << BUCK_SH) + t;
    if (node < n) sn[node] = rsqrtf(fmaxf((float)lh[t], 1.0f));
}

// --- per-bucket dst-side build: ideg->dn, rowptr, csr fill (all in LDS) -----
__global__ void build_kernel(const unsigned* __restrict__ pairs, const int* __restrict__ sbase_d,
                             int* __restrict__ rowptr, int* __restrict__ csr,
                             float* __restrict__ dn, int nbuck, int nblk, int n, int E) {
    __shared__ int lh[256], le[256], cnt[256];
    int t = threadIdx.x, u = blockIdx.x;
    lh[t] = 0; cnt[t] = 0;
    __syncthreads();
    int beg = sbase_d[u * nblk];
    int end = sbase_d[(u + 1) * nblk];
    for (int i = beg + t; i < end; i += 256) atomicAdd(&lh[pairs[i] >> 24], 1);
    __syncthreads();
    int c0 = lh[t];
    for (int off = 1; off < 256; off <<= 1) {
        int x = (t >= off) ? lh[t - off] : 0;
        __syncthreads();
        lh[t] += x;
        __syncthreads();
    }
    le[t] = lh[t] - c0;
    __syncthreads();
    int node = (u << BUCK_SH) + t;
    if (node < n) {
        rowptr[node] = beg + le[t];
        dn[node] = rsqrtf(fmaxf((float)c0, 1.0f));
    }
    if (u == nbuck - 1 && t == 0) rowptr[n] = E;
    for (int i = beg + t; i < end; i += 256) {
        unsigned pr = pairs[i];
        int bb = pr >> 24;
        int p = atomicAdd(&cnt[bb], 1);
        csr[beg + le[bb] + p] = (int)(pr & 0xFFFFFFu);
    }
}

// --- seed: scaled_h[row] = feat*sn[row] (f16), pn[row] = sn*||feat[row]|| ---
__global__ void prescale_kernel(const float* __restrict__ feat, const float* __restrict__ sn,
                                __half* __restrict__ outh, float* __restrict__ pn, int n) {
    int row  = blockIdx.x * (blockDim.x >> 6) + (threadIdx.x >> 6);
    int lane = threadIdx.x & 63;
    if (row >= n) return;
    float x = feat[(long)row * D + lane];
    float ss = x * x;
    #pragma unroll
    for (int off = 32; off; off >>= 1) ss += __shfl_xor(ss, off, 64);
    float s = sn[row];
    float v = x * s;
    float vp = __shfl_xor(v, 1, 64);
    if (!(lane & 1)) {
        *(__half2*)(outh + (long)row * D + lane) = __floats2half2_rn(v, vp);
    }
    if (lane == 0) pn[row] = s * sqrtf(ss);
}

// --- fused iteration: one wave per dst row, pure unweighted f16 row sum -----
template <int LAST>
__global__ void iter_kernel(const __half* __restrict__ cur, const float* __restrict__ feat0,
                            const int* __restrict__ rowptr, const int* __restrict__ csr_src,
                            const float* __restrict__ pn, const float* __restrict__ dn,
                            const float* __restrict__ sn,
                            __half* __restrict__ nexth, float* __restrict__ npn,
                            float* __restrict__ out, int n) {
    int row  = blockIdx.x * (blockDim.x >> 6) + (threadIdx.x >> 6);
    int lane = threadIdx.x & 63;
    if (row >= n) return;
    int g = lane >> 3, sub = lane & 7;

    float acc[8] = {0.f, 0.f, 0.f, 0.f, 0.f, 0.f, 0.f, 0.f};
    int beg = rowptr[row], end = rowptr[row + 1];
    for (int base = beg; base < end; base += 64) {
        int m = end - base; if (m > 64) m = 64;
        int s_l = (lane < m) ? csr_src[base + lane] : 0;
        int nj = (m + 7) >> 3;
        #pragma unroll 4
        for (int j = 0; j < nj; ++j) {
            int e = j * 8 + g;
            int s = __shfl(s_l, e, 64);
            if (e < m) {
                int4 raw = *(const int4*)(cur + (long)s * D + sub * 8);
                float2 f0 = __half22float2(*(__half2*)&raw.x);
                float2 f1 = __half22float2(*(__half2*)&raw.y);
                float2 f2 = __half22float2(*(__half2*)&raw.z);
                float2 f3 = __half22float2(*(__half2*)&raw.w);
                acc[0] += f0.x; acc[1] += f0.y;
                acc[2] += f1.x; acc[3] += f1.y;
                acc[4] += f2.x; acc[5] += f2.y;
                acc[6] += f3.x; acc[7] += f3.y;
            }
        }
    }
    #pragma unroll
    for (int i = 0; i < 8; ++i) {
        float a = acc[i];
        a += __shfl_xor(a, 8, 64);
        a += __shfl_xor(a, 16, 64);
        a += __shfl_xor(a, 32, 64);
        acc[i] = a;
    }
    float dd = 0.f;
    #pragma unroll
    for (int i = 0; i < 8; ++i) dd += acc[i] * acc[i];
    dd += __shfl_xor(dd, 1, 64);
    dd += __shfl_xor(dd, 2, 64);
    dd += __shfl_xor(dd, 4, 64);
    float an = sqrtf(dd);
    float scale = pn[row] / (an + EPS) * dn[row] * (1.0f - ALPHA);

    if (g == 0) {
        long fb = (long)row * D + sub * 8;
        float4 f0a = *(const float4*)(feat0 + fb);
        float4 f0b = *(const float4*)(feat0 + fb + 4);
        float nx[8];
        nx[0] = acc[0] * scale + ALPHA * f0a.x;
        nx[1] = acc[1] * scale + ALPHA * f0a.y;
        nx[2] = acc[2] * scale + ALPHA * f0a.z;
        nx[3] = acc[3] * scale + ALPHA * f0a.w;
        nx[4] = acc[4] * scale + ALPHA * f0b.x;
        nx[5] = acc[5] * scale + ALPHA * f0b.y;
        nx[6] = acc[6] * scale + ALPHA * f0b.z;
        nx[7] = acc[7] * scale + ALPHA * f0b.w;
        if (LAST) {
            float4 o0 = {nx[0], nx[1], nx[2], nx[3]};
            float4 o1 = {nx[4], nx[5], nx[6], nx[7]};
            *(float4*)(out + fb) = o0;
            *(float4*)(out + fb + 4) = o1;
        } else {
            float s = sn[row];
            __half2 h0 = __floats2half2_rn(nx[0] * s, nx[1] * s);
            __half2 h1 = __floats2half2_rn(nx[2] * s, nx[3] * s);
            __half2 h2 = __floats2half2_rn(nx[4] * s, nx[5] * s);
            __half2 h3 = __floats2half2_rn(nx[6] * s, nx[7] * s);
            int4 packed;
            packed.x = *(int*)&h0; packed.y = *(int*)&h1;
            packed.z = *(int*)&h2; packed.w = *(int*)&h3;
            *(int4*)(nexth + fb) = packed;
            float nn = 0.f;
            #pragma unroll
            for (int i = 0; i < 8; ++i) nn += nx[i] * nx[i];
            nn += __shfl_xor(nn, 1, 64);
            nn += __shfl_xor(nn, 2, 64);
            nn += __shfl_xor(nn, 4, 64);
            if (sub == 0) npn[row] = s * sqrtf(nn);
        }
    }
}

extern "C" void kernel_launch(void* const* d_in, const int* in_sizes, int n_in,
                              void* d_out, int out_size, void* d_ws, size_t ws_size,
                              hipStream_t stream) {
    const float* feat = (const float*)d_in[0];
    const int*   src  = (const int*)d_in[1];
    const int*   dst  = (const int*)d_in[2];
    float* out = (float*)d_out;

    int n = in_sizes[0] / D;      // 100000
    int E = in_sizes[1];          // 3200000

    int nbuck = (n + 255) >> BUCK_SH;        // 391 (<= 512 required)
    int nblk  = (E + CH - 1) / CH;           // 391 (<= 512 required)
    int m     = nbuck * nblk;

    // workspace layout (4B units for the small arrays)
    int* hist_d  = (int*)d_ws;               // m
    int* hist_s  = hist_d + m;               // m
    int* sbase_d = hist_s + m;               // m+1
    int* sbase_s = sbase_d + m + 1;          // m+1
    int* tot_d   = sbase_s + m + 1;          // 512
    int* tot_s   = tot_d + 512;              // 512
    int* base_d  = tot_s + 512;              // 512
    int* base_s  = base_d + 512;             // 512
    int* rowptr  = base_s + 512;             // n+1
    float* sn    = (float*)(rowptr + n + 1); // n
    float* dn    = sn + n;                   // n
    float* pn_a  = dn + n;                   // n
    float* pn_b  = pn_a + n;                 // n

    // region P (256B-aligned): packed pairs (E u32), later aliased by the two
    // f16 ping-pong feat buffers (2 * n*D halves = 25.6 MB >= 12.8 MB)
    size_t used4 = (size_t)(4 * m + 2) + 2048 + 5 * (size_t)n + 1;
    size_t offP  = (used4 * 4 + 255) & ~(size_t)255;
    unsigned* pairs  = (unsigned*)((char*)d_ws + offP);
    __half* scaled_a = (__half*)((char*)d_ws + offP);          // n*D halves
    __half* scaled_b = scaled_a + (size_t)n * D;               // n*D halves (keeps 256B align)
    size_t szP = 2 * (size_t)n * D * sizeof(__half);           // 25.6 MB (covers pairs 12.8 MB)
    // region Q (256B-aligned): skeys (E u8), later aliased by csr (E u32)
    size_t offQ = (offP + szP + 255) & ~(size_t)255;
    unsigned char* skeys = (unsigned char*)d_ws + offQ;
    int* csr = (int*)((char*)d_ws + offQ);

    int eblocks = nblk;
    // 1. coarse histograms (no global atomics)
    hist_kernel<<<eblocks, 256, 0, stream>>>(src, dst, hist_d, hist_s, nbuck, nblk, E);
    // 2. hierarchical exclusive scan of both [bucket][block] matrices
    bucket_total_kernel<<<nbuck, 256, 0, stream>>>(hist_d, hist_s, tot_d, tot_s, nblk);
    base_scan_kernel<<<1, 512, 0, stream>>>(tot_d, tot_s, base_d, base_s, nbuck);
    row_scan_kernel<<<nbuck, 512, 0, stream>>>(hist_d, hist_s, base_d, base_s,
                                               sbase_d, sbase_s, nblk, E, m);
    // 3. scatter edges into bucket-grouped arrays (packed u32 pairs, u8 skeys)
    scatter_kernel<<<eblocks, 256, 0, stream>>>(src, dst, sbase_d, sbase_s, pairs, skeys,
                                                nbuck, nblk, E);
    // 4. src-side per-node degree -> sn   (skeys consumed here)
    src_deg_kernel<<<nbuck, 256, 0, stream>>>(skeys, sbase_s, sn, nbuck, nblk, n);
    // 5. dst-side build: rowptr, dn, csr  (csr aliases skeys; pairs consumed here)
    build_kernel<<<nbuck, 256, 0, stream>>>(pairs, sbase_d, rowptr, csr, dn, nbuck, nblk, n, E);

    // 6. propagation: prescale + 3 fused iterations (f16 ping-pong aliases pairs)
    int blocks = (n + 3) / 4;  // 4 waves per 256-thread block
    prescale_kernel<<<blocks, 256, 0, stream>>>(feat, sn, scaled_a, pn_a, n);
    iter_kernel<0><<<blocks, 256, 0, stream>>>(scaled_a, feat, rowptr, csr, pn_a, dn, sn,
                                               scaled_b, pn_b, nullptr, n);
    iter_kernel<0><<<blocks, 256, 0, stream>>>(scaled_b, feat, rowptr, csr, pn_b, dn, sn,
                                               scaled_a, pn_a, nullptr, n);
    iter_kernel<1><<<blocks, 256, 0, stream>>>(scaled_a, feat, rowptr, csr, pn_a, dn, sn,
                                               nullptr, nullptr, out, n);
}

// Round 9
// 326.373 us; speedup vs baseline: 2.4477x; 1.0312x over previous
//
#include <hip/hip_runtime.h>
#include <hip/hip_fp16.h>
#include <math.h>

#define ALPHA 0.1f
#define EPS 1e-6f
#define D 64
#define CH 8192      // edges per block in hist/scatter kernels
#define BUCK_SH 8    // 256 nodes per bucket (nbuck = ceil(n/256) must be <= 512)

// --- per-block coarse histograms of dst>>8 and src>>8 (LDS, no global atomics)
__global__ void hist_kernel(const int* __restrict__ src, const int* __restrict__ dst,
                            int* __restrict__ hist_d, int* __restrict__ hist_s,
                            int nbuck, int nblk, int E) {
    __shared__ int hd[512], hs[512];
    int t = threadIdx.x, b = blockIdx.x;
    for (int u = t; u < 512; u += 256) { hd[u] = 0; hs[u] = 0; }
    __syncthreads();
    int beg = b * CH, end = min(beg + CH, E);
    for (int e = beg + t; e < end; e += 256) {
        atomicAdd(&hd[dst[e] >> BUCK_SH], 1);
        atomicAdd(&hs[src[e] >> BUCK_SH], 1);
    }
    __syncthreads();
    for (int u = t; u < nbuck; u += 256) {
        hist_d[u * nblk + b] = hd[u];   // [bucket][block] layout
        hist_s[u * nblk + b] = hs[u];
    }
}

// --- stage 1: per-bucket totals (one block per bucket, coalesced row sum) ---
__global__ void bucket_total_kernel(const int* __restrict__ hist_d, const int* __restrict__ hist_s,
                                    int* __restrict__ tot_d, int* __restrict__ tot_s, int nblk) {
    __shared__ int rd[256], rs[256];
    int u = blockIdx.x, t = threadIdx.x;
    int sd = 0, ss = 0;
    for (int b = t; b < nblk; b += 256) {
        sd += hist_d[u * nblk + b];
        ss += hist_s[u * nblk + b];
    }
    rd[t] = sd; rs[t] = ss;
    __syncthreads();
    for (int off = 128; off; off >>= 1) {
        if (t < off) { rd[t] += rd[t + off]; rs[t] += rs[t + off]; }
        __syncthreads();
    }
    if (t == 0) { tot_d[u] = rd[0]; tot_s[u] = rs[0]; }
}

// --- stage 2: exclusive scan of bucket totals (single 512-thread block) -----
__global__ void base_scan_kernel(const int* __restrict__ tot_d, const int* __restrict__ tot_s,
                                 int* __restrict__ base_d, int* __restrict__ base_s, int nbuck) {
    __shared__ int a[512], b[512];
    int t = threadIdx.x;
    int vd = (t < nbuck) ? tot_d[t] : 0;
    int vs = (t < nbuck) ? tot_s[t] : 0;
    a[t] = vd; b[t] = vs;
    __syncthreads();
    for (int off = 1; off < 512; off <<= 1) {
        int av = (t >= off) ? a[t - off] : 0;
        int bv = (t >= off) ? b[t - off] : 0;
        __syncthreads();
        a[t] += av; b[t] += bv;
        __syncthreads();
    }
    if (t < nbuck) {
        base_d[t] = a[t] - vd;   // exclusive
        base_s[t] = b[t] - vs;
    }
}

// --- stage 3: per-bucket row scan + bucket base -> scatter bases ------------
__global__ void row_scan_kernel(const int* __restrict__ hist_d, const int* __restrict__ hist_s,
                                const int* __restrict__ base_d, const int* __restrict__ base_s,
                                int* __restrict__ sbase_d, int* __restrict__ sbase_s,
                                int nblk, int E, int m) {
    __shared__ int a[512], b[512];
    int u = blockIdx.x, t = threadIdx.x;
    int hd = (t < nblk) ? hist_d[u * nblk + t] : 0;
    int hs = (t < nblk) ? hist_s[u * nblk + t] : 0;
    a[t] = hd; b[t] = hs;
    __syncthreads();
    for (int off = 1; off < 512; off <<= 1) {
        int av = (t >= off) ? a[t - off] : 0;
        int bv = (t >= off) ? b[t - off] : 0;
        __syncthreads();
        a[t] += av; b[t] += bv;
        __syncthreads();
    }
    if (t < nblk) {
        sbase_d[u * nblk + t] = base_d[u] + a[t] - hd;
        sbase_s[u * nblk + t] = base_s[u] + b[t] - hs;
    }
    if (u == 0 && t == 0) { sbase_d[m] = E; sbase_s[m] = E; }
}

// --- scatter edges into bucket-grouped arrays (LDS counters) ----------------
// pairs packed: (dst & 255) << 24 | src   (requires n < 2^24)
__global__ void scatter_kernel(const int* __restrict__ src, const int* __restrict__ dst,
                               const int* __restrict__ sbase_d, const int* __restrict__ sbase_s,
                               unsigned* __restrict__ pairs, unsigned char* __restrict__ skeys,
                               int nbuck, int nblk, int E) {
    __shared__ int cd[512], cs[512];
    int t = threadIdx.x, b = blockIdx.x;
    for (int u = t; u < nbuck; u += 256) {
        cd[u] = sbase_d[u * nblk + b];
        cs[u] = sbase_s[u * nblk + b];
    }
    __syncthreads();
    int beg = b * CH, end = min(beg + CH, E);
    for (int e = beg + t; e < end; e += 256) {
        int dv = dst[e], sv = src[e];
        int pu = atomicAdd(&cd[dv >> BUCK_SH], 1);
        pairs[pu] = ((unsigned)(dv & 255) << 24) | (unsigned)sv;
        int su = atomicAdd(&cs[sv >> BUCK_SH], 1);
        skeys[su] = (unsigned char)(sv & 255);
    }
}

// --- per-bucket src-degree count -> sn (one block per 256-node bucket) ------
__global__ void src_deg_kernel(const unsigned char* __restrict__ skeys,
                               const int* __restrict__ sbase_s,
                               float* __restrict__ sn, int nbuck, int nblk, int n) {
    __shared__ int lh[256];
    int t = threadIdx.x, u = blockIdx.x;
    lh[t] = 0;
    __syncthreads();
    int beg = sbase_s[u * nblk];
    int end = sbase_s[(u + 1) * nblk];   // u+1==nbuck -> index m -> E
    for (int i = beg + t; i < end; i += 256) atomicAdd(&lh[skeys[i]], 1);
    __syncthreads();
    int node = (u << BUCK_SH) + t;
    if (node < n) sn[node] = rsqrtf(fmaxf((float)lh[t], 1.0f));
}

// --- per-bucket dst-side build: ideg->dn, rowptr, csr fill (all in LDS) -----
__global__ void build_kernel(const unsigned* __restrict__ pairs, const int* __restrict__ sbase_d,
                             int* __restrict__ rowptr, int* __restrict__ csr,
                             float* __restrict__ dn, int nbuck, int nblk, int n, int E) {
    __shared__ int lh[256], le[256], cnt[256];
    int t = threadIdx.x, u = blockIdx.x;
    lh[t] = 0; cnt[t] = 0;
    __syncthreads();
    int beg = sbase_d[u * nblk];
    int end = sbase_d[(u + 1) * nblk];
    for (int i = beg + t; i < end; i += 256) atomicAdd(&lh[pairs[i] >> 24], 1);
    __syncthreads();
    int c0 = lh[t];
    for (int off = 1; off < 256; off <<= 1) {
        int x = (t >= off) ? lh[t - off] : 0;
        __syncthreads();
        lh[t] += x;
        __syncthreads();
    }
    le[t] = lh[t] - c0;
    __syncthreads();
    int node = (u << BUCK_SH) + t;
    if (node < n) {
        rowptr[node] = beg + le[t];
        dn[node] = rsqrtf(fmaxf((float)c0, 1.0f));
    }
    if (u == nbuck - 1 && t == 0) rowptr[n] = E;
    for (int i = beg + t; i < end; i += 256) {
        unsigned pr = pairs[i];
        int bb = pr >> 24;
        int p = atomicAdd(&cnt[bb], 1);
        csr[beg + le[bb] + p] = (int)(pr & 0xFFFFFFu);
    }
}

// --- seed: scaled_h[row] = feat*sn[row] (f16), pn[row] = sn*||feat[row]|| ---
__global__ void prescale_kernel(const float* __restrict__ feat, const float* __restrict__ sn,
                                __half* __restrict__ outh, float* __restrict__ pn, int n) {
    int row  = blockIdx.x * (blockDim.x >> 6) + (threadIdx.x >> 6);
    int lane = threadIdx.x & 63;
    if (row >= n) return;
    float x = feat[(long)row * D + lane];
    float ss = x * x;
    #pragma unroll
    for (int off = 32; off; off >>= 1) ss += __shfl_xor(ss, off, 64);
    float s = sn[row];
    float v = x * s;
    float vp = __shfl_xor(v, 1, 64);
    if (!(lane & 1)) {
        *(__half2*)(outh + (long)row * D + lane) = __floats2half2_rn(v, vp);
    }
    if (lane == 0) pn[row] = s * sqrtf(ss);
}

// --- fused iteration: one wave per dst row, packed-f16 row accumulation -----
// lane = (g,sub): g (0..7) = edge slot, sub (0..7) = 16B (8-half) column slice
template <int LAST>
__global__ void iter_kernel(const __half* __restrict__ cur, const float* __restrict__ feat0,
                            const int* __restrict__ rowptr, const int* __restrict__ csr_src,
                            const float* __restrict__ pn, const float* __restrict__ dn,
                            const float* __restrict__ sn,
                            __half* __restrict__ nexth, float* __restrict__ npn,
                            float* __restrict__ out, int n) {
    int row  = blockIdx.x * (blockDim.x >> 6) + (threadIdx.x >> 6);
    int lane = threadIdx.x & 63;
    if (row >= n) return;
    int g = lane >> 3, sub = lane & 7;

    __half2 hz = __float2half2_rn(0.f);
    __half2 hacc0 = hz, hacc1 = hz, hacc2 = hz, hacc3 = hz;
    int beg = rowptr[row], end = rowptr[row + 1];
    for (int base = beg; base < end; base += 64) {
        int m = end - base; if (m > 64) m = 64;
        int s_l = (lane < m) ? csr_src[base + lane] : 0;
        int nfull = m >> 3;        // steps where all 8 groups have a valid edge
        #pragma unroll 4
        for (int j = 0; j < nfull; ++j) {
            int s = __shfl(s_l, j * 8 + g, 64);
            int4 raw = *(const int4*)(cur + (long)s * D + sub * 8);
            hacc0 = __hadd2(hacc0, *(__half2*)&raw.x);
            hacc1 = __hadd2(hacc1, *(__half2*)&raw.y);
            hacc2 = __hadd2(hacc2, *(__half2*)&raw.z);
            hacc3 = __hadd2(hacc3, *(__half2*)&raw.w);
        }
        int e = nfull * 8 + g;     // tail step (e <= 63)
        int s = __shfl(s_l, e, 64);
        if (e < m) {
            int4 raw = *(const int4*)(cur + (long)s * D + sub * 8);
            hacc0 = __hadd2(hacc0, *(__half2*)&raw.x);
            hacc1 = __hadd2(hacc1, *(__half2*)&raw.y);
            hacc2 = __hadd2(hacc2, *(__half2*)&raw.z);
            hacc3 = __hadd2(hacc3, *(__half2*)&raw.w);
        }
    }
    float acc[8];
    { float2 f; f = __half22float2(hacc0); acc[0] = f.x; acc[1] = f.y;
      f = __half22float2(hacc1); acc[2] = f.x; acc[3] = f.y;
      f = __half22float2(hacc2); acc[4] = f.x; acc[5] = f.y;
      f = __half22float2(hacc3); acc[6] = f.x; acc[7] = f.y; }
    // reduce across the 8 edge-groups (lane bits 3..5) in f32
    #pragma unroll
    for (int i = 0; i < 8; ++i) {
        float a = acc[i];
        a += __shfl_xor(a, 8, 64);
        a += __shfl_xor(a, 16, 64);
        a += __shfl_xor(a, 32, 64);
        acc[i] = a;
    }
    float dd = 0.f;
    #pragma unroll
    for (int i = 0; i < 8; ++i) dd += acc[i] * acc[i];
    dd += __shfl_xor(dd, 1, 64);
    dd += __shfl_xor(dd, 2, 64);
    dd += __shfl_xor(dd, 4, 64);
    float an = sqrtf(dd);
    float scale = pn[row] / (an + EPS) * dn[row] * (1.0f - ALPHA);

    if (g == 0) {
        long fb = (long)row * D + sub * 8;
        float4 f0a = *(const float4*)(feat0 + fb);
        float4 f0b = *(const float4*)(feat0 + fb + 4);
        float nx[8];
        nx[0] = acc[0] * scale + ALPHA * f0a.x;
        nx[1] = acc[1] * scale + ALPHA * f0a.y;
        nx[2] = acc[2] * scale + ALPHA * f0a.z;
        nx[3] = acc[3] * scale + ALPHA * f0a.w;
        nx[4] = acc[4] * scale + ALPHA * f0b.x;
        nx[5] = acc[5] * scale + ALPHA * f0b.y;
        nx[6] = acc[6] * scale + ALPHA * f0b.z;
        nx[7] = acc[7] * scale + ALPHA * f0b.w;
        if (LAST) {
            float4 o0 = {nx[0], nx[1], nx[2], nx[3]};
            float4 o1 = {nx[4], nx[5], nx[6], nx[7]};
            *(float4*)(out + fb) = o0;
            *(float4*)(out + fb + 4) = o1;
        } else {
            float s = sn[row];
            __half2 h0 = __floats2half2_rn(nx[0] * s, nx[1] * s);
            __half2 h1 = __floats2half2_rn(nx[2] * s, nx[3] * s);
            __half2 h2 = __floats2half2_rn(nx[4] * s, nx[5] * s);
            __half2 h3 = __floats2half2_rn(nx[6] * s, nx[7] * s);
            int4 packed;
            packed.x = *(int*)&h0; packed.y = *(int*)&h1;
            packed.z = *(int*)&h2; packed.w = *(int*)&h3;
            *(int4*)(nexth + fb) = packed;
            float nn = 0.f;
            #pragma unroll
            for (int i = 0; i < 8; ++i) nn += nx[i] * nx[i];
            nn += __shfl_xor(nn, 1, 64);
            nn += __shfl_xor(nn, 2, 64);
            nn += __shfl_xor(nn, 4, 64);
            if (sub == 0) npn[row] = s * sqrtf(nn);
        }
    }
}

extern "C" void kernel_launch(void* const* d_in, const int* in_sizes, int n_in,
                              void* d_out, int out_size, void* d_ws, size_t ws_size,
                              hipStream_t stream) {
    const float* feat = (const float*)d_in[0];
    const int*   src  = (const int*)d_in[1];
    const int*   dst  = (const int*)d_in[2];
    float* out = (float*)d_out;

    int n = in_sizes[0] / D;      // 100000
    int E = in_sizes[1];          // 3200000

    int nbuck = (n + 255) >> BUCK_SH;        // 391 (<= 512 required)
    int nblk  = (E + CH - 1) / CH;           // 391 (<= 512 required)
    int m     = nbuck * nblk;

    // workspace layout (4B units for the small arrays)
    int* hist_d  = (int*)d_ws;               // m
    int* hist_s  = hist_d + m;               // m
    int* sbase_d = hist_s + m;               // m+1
    int* sbase_s = sbase_d + m + 1;          // m+1
    int* tot_d   = sbase_s + m + 1;          // 512
    int* tot_s   = tot_d + 512;              // 512
    int* base_d  = tot_s + 512;              // 512
    int* base_s  = base_d + 512;             // 512
    int* rowptr  = base_s + 512;             // n+1
    float* sn    = (float*)(rowptr + n + 1); // n
    float* dn    = sn + n;                   // n
    float* pn_a  = dn + n;                   // n
    float* pn_b  = pn_a + n;                 // n

    // region P (256B-aligned): packed pairs (E u32), later aliased by the two
    // f16 ping-pong feat buffers (2 * n*D halves = 25.6 MB >= 12.8 MB)
    size_t used4 = (size_t)(4 * m + 2) + 2048 + 5 * (size_t)n + 1;
    size_t offP  = (used4 * 4 + 255) & ~(size_t)255;
    unsigned* pairs  = (unsigned*)((char*)d_ws + offP);
    __half* scaled_a = (__half*)((char*)d_ws + offP);          // n*D halves
    __half* scaled_b = scaled_a + (size_t)n * D;               // n*D halves (keeps 256B align)
    size_t szP = 2 * (size_t)n * D * sizeof(__half);           // 25.6 MB (covers pairs 12.8 MB)
    // region Q (256B-aligned): skeys (E u8), later aliased by csr (E u32)
    size_t offQ = (offP + szP + 255) & ~(size_t)255;
    unsigned char* skeys = (unsigned char*)d_ws + offQ;
    int* csr = (int*)((char*)d_ws + offQ);

    int eblocks = nblk;
    // 1. coarse histograms (no global atomics)
    hist_kernel<<<eblocks, 256, 0, stream>>>(src, dst, hist_d, hist_s, nbuck, nblk, E);
    // 2. hierarchical exclusive scan of both [bucket][block] matrices
    bucket_total_kernel<<<nbuck, 256, 0, stream>>>(hist_d, hist_s, tot_d, tot_s, nblk);
    base_scan_kernel<<<1, 512, 0, stream>>>(tot_d, tot_s, base_d, base_s, nbuck);
    row_scan_kernel<<<nbuck, 512, 0, stream>>>(hist_d, hist_s, base_d, base_s,
                                               sbase_d, sbase_s, nblk, E, m);
    // 3. scatter edges into bucket-grouped arrays (packed u32 pairs, u8 skeys)
    scatter_kernel<<<eblocks, 256, 0, stream>>>(src, dst, sbase_d, sbase_s, pairs, skeys,
                                                nbuck, nblk, E);
    // 4. src-side per-node degree -> sn   (skeys consumed here)
    src_deg_kernel<<<nbuck, 256, 0, stream>>>(skeys, sbase_s, sn, nbuck, nblk, n);
    // 5. dst-side build: rowptr, dn, csr  (csr aliases skeys; pairs consumed here)
    build_kernel<<<nbuck, 256, 0, stream>>>(pairs, sbase_d, rowptr, csr, dn, nbuck, nblk, n, E);

    // 6. propagation: prescale + 3 fused iterations (f16 ping-pong aliases pairs)
    int blocks = (n + 3) / 4;  // 4 waves per 256-thread block
    prescale_kernel<<<blocks, 256, 0, stream>>>(feat, sn, scaled_a, pn_a, n);
    iter_kernel<0><<<blocks, 256, 0, stream>>>(scaled_a, feat, rowptr, csr, pn_a, dn, sn,
                                               scaled_b, pn_b, nullptr, n);
    iter_kernel<0><<<blocks, 256, 0, stream>>>(scaled_b, feat, rowptr, csr, pn_b, dn, sn,
                                               scaled_a, pn_a, nullptr, n);
    iter_kernel<1><<<blocks, 256, 0, stream>>>(scaled_a, feat, rowptr, csr, pn_a, dn, sn,
                                               nullptr, nullptr, out, n);
}